// Round 1
// baseline (401.034 us; speedup 1.0000x reference)
//
#include <hip/hip_runtime.h>
#include <hip/hip_bf16.h>
#include <cstdint>

typedef unsigned short u16;
typedef __attribute__((ext_vector_type(8))) __bf16 bf16x8;
typedef __attribute__((ext_vector_type(4))) float f32x4;
typedef __attribute__((ext_vector_type(8))) u16 us8;
typedef __attribute__((ext_vector_type(4))) u16 us4;

__device__ __forceinline__ float bf2f(u16 u) {
    return __uint_as_float(((unsigned int)u) << 16);
}
__device__ __forceinline__ u16 f2bf(float f) {
    unsigned int u = __float_as_uint(f);
    unsigned int r = (u + 0x7fffu + ((u >> 16) & 1u)) >> 16;
    return (u16)r;
}

__device__ __forceinline__ void gload_lds16(const void* src, void* dst) {
    __builtin_amdgcn_global_load_lds(
        (const __attribute__((address_space(1))) void*)src,
        (__attribute__((address_space(3))) void*)dst,
        16, 0, 0);
}

// ---------------------------------------------------------------------------
// Weight prep: transpose+cast weights to bf16 "BT" layout (row = output col,
// contiguous along K) so GEMM B-fragments are contiguous 16B LDS reads.
// BT1 (1024x512): cols 0-511 = mW1_top^T (center), 512-1023 = mW1_bot^T (nbr)
// BT2 (512x512)  = mW2^T ; BT3 (512x1024) = uW1^T ; BT4 (512x512) = uW2^T
// ---------------------------------------------------------------------------
__global__ void prep_weights(const float* __restrict__ mW1, const float* __restrict__ mW2,
                             const float* __restrict__ uW1, const float* __restrict__ uW2,
                             u16* __restrict__ BT1, u16* __restrict__ BT2,
                             u16* __restrict__ BT3, u16* __restrict__ BT4)
{
    int tid = blockIdx.x * 256 + threadIdx.x;           // [0, 524288)
    if (tid < 1024 * 512) {
        int j = tid >> 9, k = tid & 511;                // BT1[j*512+k]
        float v = (j < 512) ? mW1[(size_t)k * 512 + j]
                            : mW1[(size_t)(512 + k) * 512 + (j - 512)];
        BT1[tid] = f2bf(v);
        int j2 = tid >> 10, k2 = tid & 1023;            // BT3[j2*1024+k2]
        BT3[tid] = f2bf(uW1[(size_t)k2 * 512 + j2]);
    }
    if (tid < 512 * 512) {
        int j = tid >> 9, k = tid & 511;
        BT2[tid] = f2bf(mW2[(size_t)k * 512 + j]);
        BT4[tid] = f2bf(uW2[(size_t)k * 512 + j]);
    }
}

// Cast x (f32, M x 512) into cols [0,512) of xu (bf16, M x 1024)
__global__ void cast_x(const float* __restrict__ x, u16* __restrict__ xu, int total4)
{
    int i = blockIdx.x * 256 + threadIdx.x;
    if (i >= total4) return;
    int r = i >> 7, cg = i & 127;                       // 128 float4-groups per row
    float4 v = ((const float4*)x)[i];
    us4 o = { f2bf(v.x), f2bf(v.y), f2bf(v.z), f2bf(v.w) };
    *(us4*)(xu + (size_t)r * 1024 + cg * 4) = o;
}

// ---------------------------------------------------------------------------
// GEMM: C[M,N] = A[M,K] (bf16, lda) @ B (bf16, pre-transposed: BT[N][K], ldb)
// m97 structure: 128x128 tile, BK=32, 4 waves (2x2 of 64x64), double-buffered
// LDS, global_load_lds width 16, mfma_f32_16x16x32_bf16.
// ---------------------------------------------------------------------------
template<int OUTF32, int DOSILU, int DOBIAS>
__global__ __launch_bounds__(256, 2)
void gemm_bt(const u16* __restrict__ A, int lda,
             const u16* __restrict__ Bt, int ldb,
             u16* __restrict__ Cb, float* __restrict__ Cf, int ldc,
             const float* __restrict__ bias, int M, int K)
{
    __shared__ __align__(16) u16 lA[2][128 * 32];
    __shared__ __align__(16) u16 lB[2][128 * 32];

    const int tid  = threadIdx.x;
    const int wid  = tid >> 6;
    const int lane = tid & 63;
    const int lr   = lane & 15;
    const int h    = lane >> 4;
    const int m0   = blockIdx.y * 128;
    const int n0   = blockIdx.x * 128;
    const int wm   = (wid >> 1) * 64;
    const int wn   = (wid & 1) * 64;

    f32x4 acc[4][4];
#pragma unroll
    for (int i = 0; i < 4; ++i)
#pragma unroll
        for (int j = 0; j < 4; ++j)
            acc[i][j] = (f32x4){0.f, 0.f, 0.f, 0.f};

    const int NT = K >> 5;

    // tile = 128 rows x 32 cols bf16 (8KB). chunk g in [0,512): 16B each,
    // row r = g>>2, k-chunk c = g&3. Per wave: 2 calls of 64 lanes x 16B.
    auto stageA = [&](int t, int buf) {
#pragma unroll
        for (int q = 0; q < 2; ++q) {
            int gc = (wid * 2 + q) * 64 + lane;
            int r = gc >> 2, c = gc & 3;
            int grow = m0 + r; grow = grow < M ? grow : M - 1;
            const u16* src = A + (size_t)grow * lda + (t << 5) + c * 8;
            gload_lds16(src, &lA[buf][(wid * 2 + q) * 512]);
        }
    };
    auto stageB = [&](int t, int buf) {
#pragma unroll
        for (int q = 0; q < 2; ++q) {
            int gc = (wid * 2 + q) * 64 + lane;
            int r = gc >> 2, c = gc & 3;
            const u16* src = Bt + (size_t)(n0 + r) * ldb + (t << 5) + c * 8;
            gload_lds16(src, &lB[buf][(wid * 2 + q) * 512]);
        }
    };

    stageA(0, 0);
    stageB(0, 0);
    __syncthreads();

    int cur = 0;
    for (int t = 0; t < NT; ++t) {
        if (t + 1 < NT) {
            stageA(t + 1, cur ^ 1);
            stageB(t + 1, cur ^ 1);
        }
        bf16x8 af[4], bfr[4];
#pragma unroll
        for (int i = 0; i < 4; ++i) {
            int ra = wm + i * 16 + lr;
            af[i]  = *(const bf16x8*)&lA[cur][ra * 32 + h * 8];
            int rb = wn + i * 16 + lr;
            bfr[i] = *(const bf16x8*)&lB[cur][rb * 32 + h * 8];
        }
#pragma unroll
        for (int i = 0; i < 4; ++i)
#pragma unroll
            for (int j = 0; j < 4; ++j)
                acc[i][j] = __builtin_amdgcn_mfma_f32_16x16x32_bf16(af[i], bfr[j], acc[i][j], 0, 0, 0);
        __syncthreads();
        cur ^= 1;
    }

    float bv[4] = {0.f, 0.f, 0.f, 0.f};
    if (DOBIAS) {
#pragma unroll
        for (int j = 0; j < 4; ++j) bv[j] = bias[n0 + wn + j * 16 + lr];
    }
    // D layout (m89-verified): col = lane&15, row = 4*(lane>>4) + reg
#pragma unroll
    for (int i = 0; i < 4; ++i) {
        int rowb = m0 + wm + i * 16 + 4 * h;
#pragma unroll
        for (int j = 0; j < 4; ++j) {
            int gcol = n0 + wn + j * 16 + lr;
#pragma unroll
            for (int rj = 0; rj < 4; ++rj) {
                int grow = rowb + rj;
                if (grow < M) {
                    float v = acc[i][j][rj] + bv[j];
                    if (DOSILU) v = v / (1.f + __expf(-v));
                    if (OUTF32) Cf[(size_t)grow * ldc + gcol] = v;
                    else        Cb[(size_t)grow * ldc + gcol] = f2bf(v);
                }
            }
        }
    }
}

// ---------------------------------------------------------------------------
// s[row] = (1/8) * sum_k silu(c_proj[row] + n_proj[b, knn[n,k]] + mb1)
// P (bf16, M x 1024): cols 0-511 c_proj, 512-1023 n_proj. One wave per row.
// ---------------------------------------------------------------------------
__global__ void gather_silu_mean(const u16* __restrict__ P, const int* __restrict__ knn,
                                 const float* __restrict__ mb1, u16* __restrict__ S,
                                 int Nn, int M)
{
    int wid = threadIdx.x >> 6, lane = threadIdx.x & 63;
    int row = blockIdx.x * 4 + wid;
    if (row >= M) return;
    int b = row / Nn, n = row - b * Nn;
    int c0 = lane * 8;

    us8 cu = *(const us8*)(P + (size_t)row * 1024 + c0);
    float base[8], accv[8];
#pragma unroll
    for (int i = 0; i < 8; ++i) { base[i] = bf2f(cu[i]) + mb1[c0 + i]; accv[i] = 0.f; }

    const u16* Pn = P + (size_t)b * Nn * 1024 + 512 + c0;
#pragma unroll
    for (int k = 0; k < 8; ++k) {
        int j = knn[n * 8 + k];
        us8 nu = *(const us8*)(Pn + (size_t)j * 1024);
#pragma unroll
        for (int i = 0; i < 8; ++i) {
            float pv = base[i] + bf2f(nu[i]);
            accv[i] += pv / (1.f + __expf(-pv));
        }
    }
    us8 o;
#pragma unroll
    for (int i = 0; i < 8; ++i) o[i] = f2bf(accv[i] * 0.125f);
    *(us8*)(S + (size_t)row * 512 + c0) = o;
}

// ---------------------------------------------------------------------------
// In-place epilogue on Y(=d_out): v = Y + x + lat_bias[n] + ub2;  LN(v)*g + b
// One wave per row of 512.
// ---------------------------------------------------------------------------
__global__ void ln_fuse(float* __restrict__ Y, const float* __restrict__ x,
                        const float* __restrict__ lat, const float* __restrict__ ub2,
                        const float* __restrict__ g, const float* __restrict__ bta,
                        int Nn, int M)
{
    int wid = threadIdx.x >> 6, lane = threadIdx.x & 63;
    int row = blockIdx.x * 4 + wid;
    if (row >= M) return;
    int b = row / Nn, n = row - b * Nn;
    int c0 = lane * 8;

    const float* yr = Y + (size_t)row * 512 + c0;
    const float* xr = x + (size_t)row * 512 + c0;
    const float* tr = lat + (size_t)n * 512 + c0;
    float v[8];
#pragma unroll
    for (int i = 0; i < 8; ++i) v[i] = yr[i] + xr[i] + tr[i] + ub2[c0 + i];

    float s = 0.f;
#pragma unroll
    for (int i = 0; i < 8; ++i) s += v[i];
#pragma unroll
    for (int off = 32; off > 0; off >>= 1) s += __shfl_xor(s, off, 64);
    float mu = s * (1.f / 512.f);

    float q = 0.f;
#pragma unroll
    for (int i = 0; i < 8; ++i) { float d = v[i] - mu; q += d * d; }
#pragma unroll
    for (int off = 32; off > 0; off >>= 1) q += __shfl_xor(q, off, 64);
    float inv = rsqrtf(q * (1.f / 512.f) + 1e-5f);

    float* yw = Y + (size_t)row * 512 + c0;
#pragma unroll
    for (int i = 0; i < 8; ++i) yw[i] = (v[i] - mu) * inv * g[c0 + i] + bta[c0 + i];
}

extern "C" void kernel_launch(void* const* d_in, const int* in_sizes, int n_in,
                              void* d_out, int out_size, void* d_ws, size_t ws_size,
                              hipStream_t stream)
{
    const float* x   = (const float*)d_in[0];
    const float* lat = (const float*)d_in[1];
    const int*   knn = (const int*)d_in[2];
    const float* mW1 = (const float*)d_in[3];
    const float* mb1 = (const float*)d_in[4];
    const float* mW2 = (const float*)d_in[5];
    const float* mb2 = (const float*)d_in[6];
    const float* uW1 = (const float*)d_in[7];
    const float* ub1 = (const float*)d_in[8];
    const float* uW2 = (const float*)d_in[9];
    const float* ub2 = (const float*)d_in[10];
    const float* lng = (const float*)d_in[11];
    const float* lnb = (const float*)d_in[12];

    const int Nn = 10242;
    const int M  = 4 * Nn;       // 40968

    char* ws = (char*)d_ws;
    u16* BT1 = (u16*)ws; ws += (size_t)1024 * 512 * 2;
    u16* BT2 = (u16*)ws; ws += (size_t)512 * 512 * 2;
    u16* BT3 = (u16*)ws; ws += (size_t)512 * 1024 * 2;
    u16* BT4 = (u16*)ws; ws += (size_t)512 * 512 * 2;
    u16* xu  = (u16*)ws; ws += (size_t)M * 1024 * 2;   // [x_bf16 | messages]
    u16* P   = (u16*)ws; ws += (size_t)M * 1024 * 2;   // [c_proj | n_proj]
    u16* S   = (u16*)ws; ws += (size_t)M * 512 * 2;    // mean-silu; reused as T
    u16* T   = S;                                      // S dead before G3 writes T
    float* Y = (float*)d_out;

    const int MT = (M + 127) / 128;  // 321

    prep_weights<<<2048, 256, 0, stream>>>(mW1, mW2, uW1, uW2, BT1, BT2, BT3, BT4);
    cast_x<<<(M * 512 / 4 + 255) / 256, 256, 0, stream>>>(x, xu, M * 512 / 4);

    // G1: P = x @ [mW1_top | mW1_bot]   (M x 1024)
    gemm_bt<0, 0, 0><<<dim3(8, MT), 256, 0, stream>>>(xu, 1024, BT1, 512, P, nullptr, 1024, nullptr, M, 512);

    gather_silu_mean<<<(M + 3) / 4, 256, 0, stream>>>(P, knn, mb1, S, Nn, M);

    // G2: messages = S @ mW2 + mb2  -> xu cols 512..1023
    gemm_bt<0, 0, 1><<<dim3(4, MT), 256, 0, stream>>>(S, 512, BT2, 512, xu + 512, nullptr, 1024, mb2, M, 512);

    // G3: T = silu(xu @ uW1 + ub1)
    gemm_bt<0, 1, 1><<<dim3(4, MT), 256, 0, stream>>>(xu, 1024, BT3, 1024, T, nullptr, 512, ub1, M, 1024);

    // G4: Y = T @ uW2   (epilogue +ub2+lat+x+LN done in ln_fuse)
    gemm_bt<1, 0, 0><<<dim3(4, MT), 256, 0, stream>>>(T, 512, BT4, 512, nullptr, Y, 512, nullptr, M, 512);

    ln_fuse<<<(M + 3) / 4, 256, 0, stream>>>(Y, x, lat, ub2, lng, lnb, Nn, M);
}